// Round 1
// 142.753 us; speedup vs baseline: 1.1738x; 1.1738x over previous
//
#include <hip/hip_runtime.h>
#include <math.h>

#define HW 9216      // 96*96
#define C2 64
#define NCH 24       // j-chunk count (argmax grid.y)
#define EPSN 1e-8f

typedef _Float16 f16x8  __attribute__((ext_vector_type(8)));
typedef float    f32x16 __attribute__((ext_vector_type(16)));

// ---------------- kernel 1: compaction (1024 threads, shuffle scan) --------
// ilist = positions with mask>=1 (flagged i), jlist = positions with mask<1.
// Both ASCENDING in original position: jlist order is semantically required
// (first-max tie-break compares compact j; ascending compact == ascending
// original).
__global__ void compact_kernel(const int* __restrict__ mask, int* __restrict__ ilist,
                               int* __restrict__ jlist, int* __restrict__ counts) {
    int t = threadIdx.x;                 // 0..1023, each owns 9 consecutive positions
    int base = t * 9;
    unsigned fl = 0; int cnt = 0;
#pragma unroll
    for (int k = 0; k < 9; k++) {
        int f = (mask[base + k] >= 1) ? 1 : 0;
        fl |= (unsigned)f << k;
        cnt += f;
    }
    int lane = t & 63, wave = t >> 6;
    int v = cnt;
#pragma unroll
    for (int off = 1; off < 64; off <<= 1) {
        int u = __shfl_up(v, off, 64);
        if (lane >= off) v += u;
    }
    __shared__ int wsum[16];
    if (lane == 63) wsum[wave] = v;
    __syncthreads();
    int woff = 0;
#pragma unroll
    for (int w = 0; w < 16; w++) if (w < wave) woff += wsum[w];
    int incl = v + woff;
    int excl = incl - cnt;
    int posF = excl, posU = base - excl;
#pragma unroll
    for (int k = 0; k < 9; k++) {
        int p = base + k;
        if ((fl >> k) & 1u) ilist[posF++] = p; else jlist[posU++] = p;
    }
    if (t == 1023) { counts[0] = incl; counts[1] = HW - incl; }
}

// ---------------- kernel 2: fp16x2 split operand prep + amax zero ---------
// a = ah + al/2048 with ah=fp16(a), al=fp16((a-ah)*2048)  (residual exact by
// Sterbenz; x2048 keeps al in fp16 normal range). Rows:
//   aH/aL[b][p][c] : raw latter x at ilist[p]      (MFMA B operand, i side)
//   bH/bL[b][p][c] : normalized latter at jlist[p] (MFMA A operand, j side)
// Rows p >= ni (resp nj) are zero-filled to HW so 32-row tile overreads are
// benign. One thread per (b,p); 64-thread blocks to spread 288 blocks over CUs.
__global__ void prep_kernel(const float* __restrict__ x, const int* __restrict__ ilist,
                            const int* __restrict__ jlist, const int* __restrict__ counts,
                            _Float16* __restrict__ aH, _Float16* __restrict__ aL,
                            _Float16* __restrict__ bH, _Float16* __restrict__ bL,
                            unsigned long long* __restrict__ amax) {
    int t = blockIdx.x * blockDim.x + threadIdx.x;   // 0 .. 2*HW-1
    if (t >= 2 * HW) return;
    amax[t] = 0ull;                                  // ws is poisoned pre-launch
    int b = t / HW, p = t - b * HW;
    int ni = counts[0], nj = counts[1];
    const float* xl = x + (size_t)(b * 128 + 64) * HW;
    size_t rb = (size_t)t * C2;                      // row base in the f16 arrays
    float v[C2];
    // ---- a side (raw values at flagged positions)
    if (p < ni) {
        int i = ilist[p];
#pragma unroll
        for (int c = 0; c < C2; c++) v[c] = xl[(size_t)c * HW + i];
    } else {
#pragma unroll
        for (int c = 0; c < C2; c++) v[c] = 0.f;
    }
#pragma unroll
    for (int c0 = 0; c0 < C2; c0 += 8) {
        f16x8 hh, ll;
#pragma unroll
        for (int e = 0; e < 8; e++) {
            float w = v[c0 + e];
            _Float16 h = (_Float16)w;
            float r = w - (float)h;                  // exact
            hh[e] = h;
            ll[e] = (_Float16)(r * 2048.0f);
        }
        *(f16x8*)(aH + rb + c0) = hh;
        *(f16x8*)(aL + rb + c0) = ll;
    }
    // ---- b side (normalized values at unflagged positions)
    if (p < nj) {
        int j = jlist[p];
        float ss = 0.f;
#pragma unroll
        for (int c = 0; c < C2; c++) { float w = xl[(size_t)c * HW + j]; v[c] = w; ss = fmaf(w, w, ss); }
        float inv = 1.0f / fmaxf(sqrtf(ss), EPSN);
#pragma unroll
        for (int c = 0; c < C2; c++) v[c] *= inv;
    } else {
#pragma unroll
        for (int c = 0; c < C2; c++) v[c] = 0.f;
    }
#pragma unroll
    for (int c0 = 0; c0 < C2; c0 += 8) {
        f16x8 hh, ll;
#pragma unroll
        for (int e = 0; e < 8; e++) {
            float w = v[c0 + e];
            _Float16 h = (_Float16)w;
            float r = w - (float)h;
            hh[e] = h;
            ll[e] = (_Float16)(r * 2048.0f);
        }
        *(f16x8*)(bH + rb + c0) = hh;
        *(f16x8*)(bL + rb + c0) = ll;
    }
}

// ordered-float mapping: monotone bijection float -> uint32 under unsigned compare
__device__ __forceinline__ unsigned int ordf(float f) {
    unsigned int u = __float_as_uint(f);
    return (u & 0x80000000u) ? ~u : (u | 0x80000000u);
}

// ---------------- kernel 3: MFMA argmax ----------------------------------
// D[j][i] = sum_c b[j][c]*a[i][c] via v_mfma_f32_32x32x16_f16, K=64 as 4
// k-steps, 3 passes (hh into accH; ah*bl + al*bh into accC, inputs
// pre-scaled x2048). sim = accH + accC/2048; dropped al*bl/2048^2 ~ 2^-22.
// LAYOUT NOTE (do not "fix"): both A and B fragments are loaded with the
// SAME (lane-half g, elem e) -> k blocking (k = ks*16 + g*8 + e). Because
// CDNA A/B fragment layouts are k-symmetric, any bijective hardware
// k-ordering computes the same sum over the chunk — only the C/D layout
// (HW-verified: col=lane&31, row=(reg&3)+8*(reg>>2)+4*(lane>>5)) must match.
// Per wave: one 32-i strip (B operand loop-invariant in regs) x one j-chunk.
// First-max tie-break: per-lane rows scanned ascending with strict >, then
// packed-key (ordf(val)<<32 | ~j) merged across lane halves and chunks.
__global__ __launch_bounds__(256, 3) void argmax_kernel(
    const _Float16* __restrict__ aH, const _Float16* __restrict__ aL,
    const _Float16* __restrict__ bH, const _Float16* __restrict__ bL,
    const int* __restrict__ ilist, const int* __restrict__ counts,
    unsigned long long* __restrict__ amax)
{
    int ni = counts[0];
    if (blockIdx.x * 128 >= ni) return;              // dead block (ni==0 -> all exit)
    int nj = counts[1];
    int b = blockIdx.z, s = blockIdx.y;
    int wave = threadIdx.x >> 6, lane = threadIdx.x & 63;
    int strip = blockIdx.x * 4 + wave;
    if (strip * 32 >= ni) return;                    // wave-uniform, no barriers below
    int g = lane >> 5, ln = lane & 31;
    int il = strip * 32 + ln;                        // compact i (output column)

    // B operand (a rows), loop-invariant: k = ks*16 + g*8 + e
    const _Float16* ar  = aH + ((size_t)b * HW + il) * C2 + g * 8;
    const _Float16* arl = aL + ((size_t)b * HW + il) * C2 + g * 8;
    f16x8 ah0 = *(const f16x8*)(ar);
    f16x8 ah1 = *(const f16x8*)(ar + 16);
    f16x8 ah2 = *(const f16x8*)(ar + 32);
    f16x8 ah3 = *(const f16x8*)(ar + 48);
    f16x8 al0 = *(const f16x8*)(arl);
    f16x8 al1 = *(const f16x8*)(arl + 16);
    f16x8 al2 = *(const f16x8*)(arl + 32);
    f16x8 al3 = *(const f16x8*)(arl + 48);

    int njt = (nj + 31) >> 5;
    int tpc = (njt + NCH - 1) / NCH;
    int jt0 = s * tpc, jt1 = min(jt0 + tpc, njt);
    float bestv = -INFINITY; int bestj = -1;
    const _Float16* bHb = bH + ((size_t)b * HW + ln) * C2 + g * 8;
    const _Float16* bLb = bL + ((size_t)b * HW + ln) * C2 + g * 8;

    for (int jt = jt0; jt < jt1; ++jt) {
        int jb = jt << 5;
        const _Float16* bhr = bHb + (size_t)jb * C2;
        const _Float16* blr = bLb + (size_t)jb * C2;
        f16x8 bh0 = *(const f16x8*)(bhr);
        f16x8 bh1 = *(const f16x8*)(bhr + 16);
        f16x8 bh2 = *(const f16x8*)(bhr + 32);
        f16x8 bh3 = *(const f16x8*)(bhr + 48);
        f16x8 bl0 = *(const f16x8*)(blr);
        f16x8 bl1 = *(const f16x8*)(blr + 16);
        f16x8 bl2 = *(const f16x8*)(blr + 32);
        f16x8 bl3 = *(const f16x8*)(blr + 48);
        f32x16 accH = {}, accC = {};
        accH = __builtin_amdgcn_mfma_f32_32x32x16_f16(bh0, ah0, accH, 0, 0, 0);
        accC = __builtin_amdgcn_mfma_f32_32x32x16_f16(bh0, al0, accC, 0, 0, 0);
        accC = __builtin_amdgcn_mfma_f32_32x32x16_f16(bl0, ah0, accC, 0, 0, 0);
        accH = __builtin_amdgcn_mfma_f32_32x32x16_f16(bh1, ah1, accH, 0, 0, 0);
        accC = __builtin_amdgcn_mfma_f32_32x32x16_f16(bh1, al1, accC, 0, 0, 0);
        accC = __builtin_amdgcn_mfma_f32_32x32x16_f16(bl1, ah1, accC, 0, 0, 0);
        accH = __builtin_amdgcn_mfma_f32_32x32x16_f16(bh2, ah2, accH, 0, 0, 0);
        accC = __builtin_amdgcn_mfma_f32_32x32x16_f16(bh2, al2, accC, 0, 0, 0);
        accC = __builtin_amdgcn_mfma_f32_32x32x16_f16(bl2, ah2, accC, 0, 0, 0);
        accH = __builtin_amdgcn_mfma_f32_32x32x16_f16(bh3, ah3, accH, 0, 0, 0);
        accC = __builtin_amdgcn_mfma_f32_32x32x16_f16(bh3, al3, accC, 0, 0, 0);
        accC = __builtin_amdgcn_mfma_f32_32x32x16_f16(bl3, ah3, accC, 0, 0, 0);
        // scan registers in ascending-j order (strict > => first max)
#pragma unroll
        for (int r = 0; r < 16; ++r) {
            int row = (r & 3) + 8 * (r >> 2) + 4 * g;
            int j = jb + row;
            float vv = fmaf(accC[r], 4.8828125e-4f /*2^-11*/, accH[r]);
            if (j < nj && vv > bestv) { bestv = vv; bestj = j; }
        }
    }
    unsigned long long key = ((unsigned long long)ordf(bestv) << 32) |
                             (unsigned long long)(~(unsigned int)bestj);
    unsigned long long other = __shfl_xor(key, 32, 64);   // merge lane halves
    if (other > key) key = other;
    // high word > ordf(-inf) iff at least one half found a (finite) candidate
    if (g == 0 && il < ni && (unsigned)(key >> 32) > 0x007FFFFFu) {
        atomicMax(&amax[(size_t)b * HW + ilist[il]], key);   // original position
    }
}

// ---------------- kernel 4: fused epilogue (copy + decode + gather) -------
__global__ void epilogue_kernel(const float4* __restrict__ x4, const float* __restrict__ x,
                                const int* __restrict__ mask,
                                const unsigned long long* __restrict__ amax,
                                const int* __restrict__ jlist, float4* __restrict__ out4) {
    const int q = HW / 4;                            // 2304
    int t = blockIdx.x * blockDim.x + threadIdx.x;   // 0 .. 2*192*q-1
    if (t >= 2 * 192 * q) return;
    int pos4 = t % q;
    int c = (t / q) % 192;
    int b = t / (192 * q);
    if (c < 128) {
        out4[t] = x4[((size_t)b * 128 + c) * q + pos4];
    } else {
        float4 v = make_float4(0.f, 0.f, 0.f, 0.f);
        float* vp = &v.x;
        int pos = pos4 * 4;
        const float* xf = x + (size_t)(b * 128 + (c - 128)) * HW;
#pragma unroll
        for (int k = 0; k < 4; k++) {
            int p = pos + k;
            if (mask[p] >= 1) {
                unsigned long long key = amax[(size_t)b * HW + p];
                int j = 0;                           // nj==0 -> argmax of all-NEG row = 0
                if (key != 0ull) j = jlist[(int)(~(unsigned int)key)];
                vp[k] = xf[j];
            }
        }
        out4[t] = v;
    }
}

extern "C" void kernel_launch(void* const* d_in, const int* in_sizes, int n_in,
                              void* d_out, int out_size, void* d_ws, size_t ws_size,
                              hipStream_t stream) {
    const float* x = (const float*)d_in[0];
    const int* mask = (const int*)d_in[1];
    float4* out4 = (float4*)d_out;

    // workspace layout (128B-aligned):
    //   counts(0,8B) | ilist(128) | jlist(36992) | amax(73856, 147456B)
    //   aH(221312) | aL(+2359296) | bH | bL   -- each 2*HW*64 f16 = 2359296 B
    // total = 221312 + 4*2359296 = 9658496 B
    char* ws = (char*)d_ws;
    int*   counts = (int*)ws;
    int*   ilist  = (int*)(ws + 128);
    int*   jlist  = (int*)(ws + 128 + 36864);
    unsigned long long* amax = (unsigned long long*)(ws + 73856);
    _Float16* aH = (_Float16*)(ws + 221312);
    _Float16* aL = (_Float16*)(ws + 221312 + 1 * 2359296);
    _Float16* bH = (_Float16*)(ws + 221312 + 2 * 2359296);
    _Float16* bL = (_Float16*)(ws + 221312 + 3 * 2359296);

    // 1) compaction
    compact_kernel<<<1, 1024, 0, stream>>>(mask, ilist, jlist, counts);
    // 2) fp16x2 split operands + amax zeroing (64-thread blocks for CU spread)
    prep_kernel<<<(2 * HW + 63) / 64, 64, 0, stream>>>(x, ilist, jlist, counts,
                                                       aH, aL, bH, bL, amax);
    // 3) MFMA argmax: grid (i-strip groups, j-chunks, batch)
    {
        dim3 grid(HW / 128, NCH, 2);                 // 72 x 24 x 2
        argmax_kernel<<<grid, 256, 0, stream>>>(aH, aL, bH, bL, ilist, counts, amax);
    }
    // 4) fused copy + decode + gather
    {
        int n = 2 * 192 * (HW / 4);
        epilogue_kernel<<<(n + 255) / 256, 256, 0, stream>>>((const float4*)x, x, mask,
                                                             amax, jlist, out4);
    }
}

// Round 2
// 109.373 us; speedup vs baseline: 1.5320x; 1.3052x over previous
//
#include <hip/hip_runtime.h>
#include <math.h>

#define HW 9216      // 96*96
#define C2 64
#define NSTRIP 288   // HW/32 row-tiles (worst case)
#define NCH 16       // j-chunk count (argmax grid.y)
#define EPSN 1e-8f

typedef _Float16 f16x8  __attribute__((ext_vector_type(8)));
typedef float    f32x16 __attribute__((ext_vector_type(16)));

// ---------------- kernel 1: compaction (1024 threads, shuffle scan) --------
// ilist = positions with mask>=1 (flagged i), jlist = positions with mask<1.
// Both ASCENDING in original position (jlist order is semantically required:
// first-max tie-break compares compact j; ascending compact == ascending
// original).
__global__ void compact_kernel(const int* __restrict__ mask, int* __restrict__ ilist,
                               int* __restrict__ jlist, int* __restrict__ counts) {
    int t = threadIdx.x;                 // 0..1023, each owns 9 consecutive positions
    int base = t * 9;
    unsigned fl = 0; int cnt = 0;
#pragma unroll
    for (int k = 0; k < 9; k++) {
        int f = (mask[base + k] >= 1) ? 1 : 0;
        fl |= (unsigned)f << k;
        cnt += f;
    }
    int lane = t & 63, wave = t >> 6;
    int v = cnt;
#pragma unroll
    for (int off = 1; off < 64; off <<= 1) {
        int u = __shfl_up(v, off, 64);
        if (lane >= off) v += u;
    }
    __shared__ int wsum[16];
    if (lane == 63) wsum[wave] = v;
    __syncthreads();
    int woff = 0;
#pragma unroll
    for (int w = 0; w < 16; w++) if (w < wave) woff += wsum[w];
    int incl = v + woff;
    int excl = incl - cnt;
    int posF = excl, posU = base - excl;
#pragma unroll
    for (int k = 0; k < 9; k++) {
        int p = base + k;
        if ((fl >> k) & 1u) ilist[posF++] = p; else jlist[posU++] = p;
    }
    if (t == 1023) { counts[0] = incl; counts[1] = HW - incl; }
}

// ---------------- kernel 2: row norms for ALL positions --------------------
// 8 lanes per row (lane bits 0..2 = channel chunk), shuffle-reduce the sum of
// squares, lane cc==0 writes 1/max(||row||,eps). Coalesced: at fixed e the
// wave reads 8 channels x 8 consecutive positions (8 x 32B segments).
__global__ void norm_kernel(const float* __restrict__ x, float* __restrict__ invAll) {
    int t = blockIdx.x * 256 + threadIdx.x;      // 0 .. 2*HW*8-1
    int cc = t & 7;
    int pb = t >> 3;                             // b*HW + p
    int b = pb / HW, p = pb - b * HW;
    const float* xl = x + (size_t)(b * 128 + 64) * HW + p;
    float ss = 0.f;
#pragma unroll
    for (int e = 0; e < 8; e++) { float w = xl[(size_t)(cc * 8 + e) * HW]; ss = fmaf(w, w, ss); }
    ss += __shfl_xor(ss, 1, 64);
    ss += __shfl_xor(ss, 2, 64);
    ss += __shfl_xor(ss, 4, 64);
    if (cc == 0) invAll[pb] = 1.0f / fmaxf(sqrtf(ss), EPSN);
}

// ---------------- kernel 3: fragment-packed fp16x2 operand prep -----------
// a = ah + al/2048 with ah=fp16(a), al=fp16((a-ah)*2048) (residual exact by
// Sterbenz; x2048 keeps al in fp16 normal range).
// PACKED LAYOUT (must match argmax loads exactly):
//   P[b][tile][ks][lane][e]  with  lane = g*32 + (row&31),  logical
//   k = ks*16 + g*8 + e,  row = tile*32 + (lane&31).
// Side 0 (a): raw latter rows gathered via ilist. Side 1 (b): normalized
// latter rows gathered via jlist (f32 inv from norm_kernel; fp16 inv would
// perturb whole rows by ~5e-4 and risk argmax flips).
// Rows p >= count are zero-filled so tile overreads are benign (guarded in
// the argmax scan anyway). One thread per (b,side,row,cc): 1 fragment chunk.
__global__ void pack_kernel(const float* __restrict__ x, const int* __restrict__ ilist,
                            const int* __restrict__ jlist, const int* __restrict__ counts,
                            const float* __restrict__ invAll,
                            _Float16* __restrict__ aH, _Float16* __restrict__ aL,
                            _Float16* __restrict__ bH, _Float16* __restrict__ bL,
                            unsigned long long* __restrict__ amax) {
    int pslot = blockIdx.x * 256 + threadIdx.x;  // 0..HW-1 (row slot)
    int cc = blockIdx.y;                         // 0..7  (ks = cc>>1, g = cc&1)
    int z = blockIdx.z;                          // 0..3  (b = z>>1, side = z&1)
    int b = z >> 1, side = z & 1;
    if (side == 0 && cc == 0) amax[(size_t)b * HW + pslot] = 0ull;   // ws poisoned pre-launch
    int cnt = counts[side];                      // counts[0]=ni, counts[1]=nj
    const int* list = side ? jlist : ilist;
    float v[8];
    if (pslot < cnt) {
        int row = list[pslot];
        const float* xl = x + (size_t)(b * 128 + 64) * HW + row;
        float scale = side ? invAll[b * HW + row] : 1.0f;
#pragma unroll
        for (int e = 0; e < 8; e++) v[e] = xl[(size_t)(cc * 8 + e) * HW] * scale;
    } else {
#pragma unroll
        for (int e = 0; e < 8; e++) v[e] = 0.f;
    }
    f16x8 hh, ll;
#pragma unroll
    for (int e = 0; e < 8; e++) {
        float w = v[e];
        _Float16 h = (_Float16)w;
        hh[e] = h;
        ll[e] = (_Float16)((w - (float)h) * 2048.0f);
    }
    int ks = cc >> 1, g = cc & 1;
    int strip = pslot >> 5, ln = pslot & 31;
    size_t off = ((((size_t)b * NSTRIP + strip) * 4 + ks) * 64 + (g * 32 + ln)) * 8;
    _Float16* dh = side ? bH : aH;
    _Float16* dl = side ? bL : aL;
    *(f16x8*)(dh + off) = hh;
    *(f16x8*)(dl + off) = ll;
}

// ordered-float mapping: monotone bijection float -> uint32 under unsigned compare
__device__ __forceinline__ unsigned int ordf(float f) {
    unsigned int u = __float_as_uint(f);
    return (u & 0x80000000u) ? ~u : (u | 0x80000000u);
}

// ---------------- kernel 4: MFMA argmax ----------------------------------
// D[j][i] = sum_c b[j][c]*a[i][c] via v_mfma_f32_32x32x16_f16, K=64 as 4
// k-steps, 3 passes (hh into accH; ah*bl + al*bh into accC, inputs
// pre-scaled x2048). sim = accH + accC/2048; dropped al*bl/2048^2 ~ 2^-22.
// All fragment loads are CONTIGUOUS 1KB wave loads from the packed arrays
// (lane l reads P[tile][ks][l][0..7]) — register contents identical to the
// verified round-1 mapping (k = ks*16 + g*8 + e for BOTH operands; C/D:
// col=lane&31, row=(reg&3)+8*(reg>>2)+4*(lane>>5)).
// Per wave: one 32-i strip (a-frags loop-invariant in regs) x one j-chunk.
// First-max tie-break: per-lane rows scanned ascending with strict >, then
// packed-key (ordf(val)<<32 | ~j) merged across lane halves and chunks.
__global__ __launch_bounds__(256, 4) void argmax_kernel(
    const _Float16* __restrict__ aH, const _Float16* __restrict__ aL,
    const _Float16* __restrict__ bH, const _Float16* __restrict__ bL,
    const int* __restrict__ ilist, const int* __restrict__ counts,
    unsigned long long* __restrict__ amax)
{
    int ni = counts[0];
    if (blockIdx.x * 128 >= ni) return;              // dead block (ni==0 -> all exit)
    int nj = counts[1];
    int b = blockIdx.z, s = blockIdx.y;
    int wave = threadIdx.x >> 6, l = threadIdx.x & 63;
    int strip = blockIdx.x * 4 + wave;
    if (strip * 32 >= ni) return;                    // wave-uniform, no barriers below
    int g = l >> 5, ln = l & 31;
    int il = strip * 32 + ln;                        // compact i (output column)

    const f16x8* apH = (const f16x8*)aH + ((size_t)b * NSTRIP + strip) * 256 + l;
    const f16x8* apL = (const f16x8*)aL + ((size_t)b * NSTRIP + strip) * 256 + l;
    f16x8 ah0 = apH[0], ah1 = apH[64], ah2 = apH[128], ah3 = apH[192];
    f16x8 al0 = apL[0], al1 = apL[64], al2 = apL[128], al3 = apL[192];

    int njt = (nj + 31) >> 5;
    int tpc = (njt + NCH - 1) / NCH;
    int jt0 = s * tpc, jt1 = min(jt0 + tpc, njt);
    float bestv = -INFINITY; int bestj = -1;
    const f16x8* bpH0 = (const f16x8*)bH + (size_t)b * NSTRIP * 256 + l;
    const f16x8* bpL0 = (const f16x8*)bL + (size_t)b * NSTRIP * 256 + l;

    for (int jt = jt0; jt < jt1; ++jt) {
        const f16x8* bpH = bpH0 + (size_t)jt * 256;
        const f16x8* bpL = bpL0 + (size_t)jt * 256;
        f16x8 bh0 = bpH[0], bh1 = bpH[64], bh2 = bpH[128], bh3 = bpH[192];
        f16x8 bl0 = bpL[0], bl1 = bpL[64], bl2 = bpL[128], bl3 = bpL[192];
        f32x16 accH = {}, accC = {};
        accH = __builtin_amdgcn_mfma_f32_32x32x16_f16(bh0, ah0, accH, 0, 0, 0);
        accC = __builtin_amdgcn_mfma_f32_32x32x16_f16(bh0, al0, accC, 0, 0, 0);
        accC = __builtin_amdgcn_mfma_f32_32x32x16_f16(bl0, ah0, accC, 0, 0, 0);
        accH = __builtin_amdgcn_mfma_f32_32x32x16_f16(bh1, ah1, accH, 0, 0, 0);
        accC = __builtin_amdgcn_mfma_f32_32x32x16_f16(bh1, al1, accC, 0, 0, 0);
        accC = __builtin_amdgcn_mfma_f32_32x32x16_f16(bl1, ah1, accC, 0, 0, 0);
        accH = __builtin_amdgcn_mfma_f32_32x32x16_f16(bh2, ah2, accH, 0, 0, 0);
        accC = __builtin_amdgcn_mfma_f32_32x32x16_f16(bh2, al2, accC, 0, 0, 0);
        accC = __builtin_amdgcn_mfma_f32_32x32x16_f16(bl2, ah2, accC, 0, 0, 0);
        accH = __builtin_amdgcn_mfma_f32_32x32x16_f16(bh3, ah3, accH, 0, 0, 0);
        accC = __builtin_amdgcn_mfma_f32_32x32x16_f16(bh3, al3, accC, 0, 0, 0);
        accC = __builtin_amdgcn_mfma_f32_32x32x16_f16(bl3, ah3, accC, 0, 0, 0);
        int jb = jt << 5;
        // scan registers in ascending-j order (strict > => first max)
#pragma unroll
        for (int r = 0; r < 16; ++r) {
            int row = (r & 3) + 8 * (r >> 2) + 4 * g;
            int j = jb + row;
            float vv = fmaf(accC[r], 4.8828125e-4f /*2^-11*/, accH[r]);
            if (j < nj && vv > bestv) { bestv = vv; bestj = j; }
        }
    }
    unsigned long long key = ((unsigned long long)ordf(bestv) << 32) |
                             (unsigned long long)(~(unsigned int)bestj);
    unsigned long long other = __shfl_xor(key, 32, 64);   // merge lane halves
    if (other > key) key = other;
    // high word > ordf(-inf) iff at least one half found a (finite) candidate
    if (g == 0 && il < ni && (unsigned)(key >> 32) > 0x007FFFFFu) {
        atomicMax(&amax[(size_t)b * HW + ilist[il]], key);   // original position
    }
}

// ---------------- kernel 5: fused epilogue (copy + decode + gather) -------
__global__ void epilogue_kernel(const float4* __restrict__ x4, const float* __restrict__ x,
                                const int* __restrict__ mask,
                                const unsigned long long* __restrict__ amax,
                                const int* __restrict__ jlist, float4* __restrict__ out4) {
    const int q = HW / 4;                            // 2304
    int t = blockIdx.x * blockDim.x + threadIdx.x;   // 0 .. 2*192*q-1
    if (t >= 2 * 192 * q) return;
    int pos4 = t % q;
    int c = (t / q) % 192;
    int b = t / (192 * q);
    if (c < 128) {
        out4[t] = x4[((size_t)b * 128 + c) * q + pos4];
    } else {
        float4 v = make_float4(0.f, 0.f, 0.f, 0.f);
        float* vp = &v.x;
        int pos = pos4 * 4;
        const float* xf = x + (size_t)(b * 128 + (c - 128)) * HW;
#pragma unroll
        for (int k = 0; k < 4; k++) {
            int p = pos + k;
            if (mask[p] >= 1) {
                unsigned long long key = amax[(size_t)b * HW + p];
                int j = 0;                           // nj==0 -> argmax of all-NEG row = 0
                if (key != 0ull) j = jlist[(int)(~(unsigned int)key)];
                vp[k] = xf[j];
            }
        }
        out4[t] = v;
    }
}

extern "C" void kernel_launch(void* const* d_in, const int* in_sizes, int n_in,
                              void* d_out, int out_size, void* d_ws, size_t ws_size,
                              hipStream_t stream) {
    const float* x = (const float*)d_in[0];
    const int* mask = (const int*)d_in[1];
    float4* out4 = (float4*)d_out;

    // workspace layout (128B-aligned):
    //   counts @0 (8B) | ilist @128 (36864) | jlist @36992 (36864)
    //   amax @73856 (147456) | invAll @221312 (73728)
    //   aH @295040 | aL | bH | bL  -- each 2*288*4*64*8 f16 = 2359296 B
    // total = 295040 + 4*2359296 = 9732224 B
    char* ws = (char*)d_ws;
    int*   counts = (int*)ws;
    int*   ilist  = (int*)(ws + 128);
    int*   jlist  = (int*)(ws + 36992);
    unsigned long long* amax = (unsigned long long*)(ws + 73856);
    float* invAll = (float*)(ws + 221312);
    _Float16* aH = (_Float16*)(ws + 295040);
    _Float16* aL = (_Float16*)(ws + 295040 + 1 * 2359296);
    _Float16* bH = (_Float16*)(ws + 295040 + 2 * 2359296);
    _Float16* bL = (_Float16*)(ws + 295040 + 3 * 2359296);

    // 1) compaction
    compact_kernel<<<1, 1024, 0, stream>>>(mask, ilist, jlist, counts);
    // 2) row norms (all positions, coalesced, 2304 waves)
    norm_kernel<<<(2 * HW * 8) / 256, 256, 0, stream>>>(x, invAll);
    // 3) fragment-packed fp16x2 operands + amax zeroing (4608 waves)
    {
        dim3 grid(HW / 256, 8, 4);                   // 36 x (ks,g) x (b,side)
        pack_kernel<<<grid, 256, 0, stream>>>(x, ilist, jlist, counts, invAll,
                                              aH, aL, bH, bL, amax);
    }
    // 4) MFMA argmax: grid (i-strip groups, j-chunks, batch)
    {
        dim3 grid(NSTRIP / 4, NCH, 2);               // 72 x 16 x 2
        argmax_kernel<<<grid, 256, 0, stream>>>(aH, aL, bH, bL, ilist, counts, amax);
    }
    // 5) fused copy + decode + gather
    {
        int n = 2 * 192 * (HW / 4);
        epilogue_kernel<<<(n + 255) / 256, 256, 0, stream>>>((const float4*)x, x, mask,
                                                             amax, jlist, out4);
    }
}

// Round 3
// 109.060 us; speedup vs baseline: 1.5364x; 1.0029x over previous
//
#include <hip/hip_runtime.h>
#include <math.h>

#define HW 9216      // 96*96
#define C2 64
#define NSTRIP 288   // HW/32 row-tiles (worst case)
#define NCH 16       // j-chunk count (argmax grid.y)
#define EPSN 1e-8f

typedef _Float16 f16x8  __attribute__((ext_vector_type(8)));
typedef float    f32x16 __attribute__((ext_vector_type(16)));

// ---------------- kernel 1: compaction (1024 threads, shuffle scan) --------
// ilist = positions with mask>=1 (flagged i), jlist = positions with mask<1.
// Both ASCENDING in original position (first-max tie-break compares compact
// j; ascending compact == ascending original). Also emits the inverse map
// slotmap[p] = slot | (flag<<31) so pack can run in position order.
__global__ void compact_kernel(const int* __restrict__ mask, int* __restrict__ ilist,
                               int* __restrict__ jlist, int* __restrict__ slotmap,
                               int* __restrict__ counts) {
    int t = threadIdx.x;                 // 0..1023, each owns 9 consecutive positions
    int base = t * 9;
    unsigned fl = 0; int cnt = 0;
#pragma unroll
    for (int k = 0; k < 9; k++) {
        int f = (mask[base + k] >= 1) ? 1 : 0;
        fl |= (unsigned)f << k;
        cnt += f;
    }
    int lane = t & 63, wave = t >> 6;
    int v = cnt;
#pragma unroll
    for (int off = 1; off < 64; off <<= 1) {
        int u = __shfl_up(v, off, 64);
        if (lane >= off) v += u;
    }
    __shared__ int wsum[16];
    if (lane == 63) wsum[wave] = v;
    __syncthreads();
    int woff = 0;
#pragma unroll
    for (int w = 0; w < 16; w++) if (w < wave) woff += wsum[w];
    int incl = v + woff;
    int excl = incl - cnt;
    int posF = excl, posU = base - excl;
#pragma unroll
    for (int k = 0; k < 9; k++) {
        int p = base + k;
        if ((fl >> k) & 1u) { slotmap[p] = posF | 0x80000000; ilist[posF++] = p; }
        else               { slotmap[p] = posU;              jlist[posU++] = p; }
    }
    if (t == 1023) { counts[0] = incl; counts[1] = HW - incl; }
}

// ---------------- kernel 2: row norms for ALL positions --------------------
// 8 lanes per row (lane bits 0..2 = channel chunk), shuffle-reduce the sum of
// squares, lane cc==0 writes 1/max(||row||,eps).
__global__ void norm_kernel(const float* __restrict__ x, float* __restrict__ invAll) {
    int t = blockIdx.x * 256 + threadIdx.x;      // 0 .. 2*HW*8-1
    int cc = t & 7;
    int pb = t >> 3;                             // b*HW + p
    int b = pb / HW, p = pb - b * HW;
    const float* xl = x + (size_t)(b * 128 + 64) * HW + p;
    float ss = 0.f;
#pragma unroll
    for (int e = 0; e < 8; e++) { float w = xl[(size_t)(cc * 8 + e) * HW]; ss = fmaf(w, w, ss); }
    ss += __shfl_xor(ss, 1, 64);
    ss += __shfl_xor(ss, 2, 64);
    ss += __shfl_xor(ss, 4, 64);
    if (cc == 0) invAll[pb] = 1.0f / fmaxf(sqrtf(ss), EPSN);
}

// ---------------- kernel 3: fragment-packed fp16x2 operand prep -----------
// POSITION-ORDER (fully coalesced x reads: 64 consecutive p per wave-load,
// each row read exactly once since ni+nj = HW). a = ah + al/2048 with
// ah=fp16(a), al=fp16((a-ah)*2048) (residual exact by Sterbenz).
// PACKED LAYOUT (must match argmax loads exactly):
//   P[b][tile][ks][lane][e], lane = g*32 + (slot&31), k = ks*16 + g*8 + e.
// Flagged rows -> aH/aL (raw); unflagged -> bH/bL (scaled by f32 inv).
// NO zero-fill: tail-tile slots beyond the counts keep poison; argmax guards
// every use (j<nj scan guard, il<ni commit guard; 0xAA f16 is finite).
__global__ void pack_kernel(const float* __restrict__ x, const int* __restrict__ slotmap,
                            const float* __restrict__ invAll,
                            _Float16* __restrict__ aH, _Float16* __restrict__ aL,
                            _Float16* __restrict__ bH, _Float16* __restrict__ bL,
                            unsigned long long* __restrict__ amax) {
    int p = blockIdx.x * 256 + threadIdx.x;      // 0..HW-1 (position)
    int cc = blockIdx.y;                         // 0..7  (ks = cc>>1, g = cc&1)
    int b = blockIdx.z;                          // 0..1
    if (cc == 0) amax[(size_t)b * HW + p] = 0ull;    // ws poisoned pre-launch
    int sm = slotmap[p];
    int flagged = (sm >> 31) & 1;                // 1 -> a side, 0 -> b side
    int slot = sm & 0x7fffffff;
    const float* xl = x + (size_t)(b * 128 + 64) * HW + p;
    float scale = flagged ? 1.0f : invAll[b * HW + p];
    f16x8 hh, ll;
#pragma unroll
    for (int e = 0; e < 8; e++) {
        float w = xl[(size_t)(cc * 8 + e) * HW] * scale;
        _Float16 h = (_Float16)w;
        hh[e] = h;
        ll[e] = (_Float16)((w - (float)h) * 2048.0f);
    }
    int ks = cc >> 1, g = cc & 1;
    int strip = slot >> 5, ln = slot & 31;
    size_t off = ((((size_t)b * NSTRIP + strip) * 4 + ks) * 64 + (g * 32 + ln)) * 8;
    _Float16* dh = flagged ? aH : bH;
    _Float16* dl = flagged ? aL : bL;
    *(f16x8*)(dh + off) = hh;
    *(f16x8*)(dl + off) = ll;
}

// ordered-float mapping: monotone bijection float -> uint32 under unsigned compare
__device__ __forceinline__ unsigned int ordf(float f) {
    unsigned int u = __float_as_uint(f);
    return (u & 0x80000000u) ? ~u : (u | 0x80000000u);
}

// ---------------- kernel 4: MFMA argmax, 2 i-strips per wave --------------
// D[j][i] = sum_c b[j][c]*a[i][c] via v_mfma_f32_32x32x16_f16, K=64 as 4
// k-steps, 3 passes (hh into cH; ah*bl + al*bh into cC, inputs pre-scaled
// x2048). sim = cH + cC/2048; dropped al*bl/2048^2 ~ 2^-22.
// Each wave owns 64 i-rows (2 strips) so every 8KB b-tile load feeds 24
// MFMAs (halves L2 b-traffic vs 1 strip). Register contents identical to
// the verified round-2 mapping (k = ks*16 + g*8 + e both operands; C/D:
// col=lane&31, row=(reg&3)+8*(reg>>2)+4*(lane>>5)).
// First-max tie-break: per-lane rows scanned ascending with strict >, then
// packed-key (ordf(val)<<32 | ~j) merged across lane halves and chunks.
__global__ __launch_bounds__(256, 2) void argmax_kernel(
    const _Float16* __restrict__ aH, const _Float16* __restrict__ aL,
    const _Float16* __restrict__ bH, const _Float16* __restrict__ bL,
    const int* __restrict__ ilist, const int* __restrict__ counts,
    unsigned long long* __restrict__ amax)
{
    int ni = counts[0];
    if (blockIdx.x * 256 >= ni) return;              // dead block (ni==0 -> all exit)
    int nj = counts[1];
    int b = blockIdx.z, s = blockIdx.y;
    int wave = threadIdx.x >> 6, l = threadIdx.x & 63;
    int base = (blockIdx.x * 4 + wave) * 64;         // first i-row of this wave
    if (base >= ni) return;                          // wave-uniform, no barriers below
    int g = l >> 5, ln = l & 31;
    int strip0 = base >> 5;

    const f16x8* apH = (const f16x8*)aH + ((size_t)b * NSTRIP + strip0) * 256 + l;
    const f16x8* apL = (const f16x8*)aL + ((size_t)b * NSTRIP + strip0) * 256 + l;
    f16x8 xh0 = apH[0],   xh1 = apH[64],  xh2 = apH[128], xh3 = apH[192];   // strip0 H
    f16x8 xl0 = apL[0],   xl1 = apL[64],  xl2 = apL[128], xl3 = apL[192];   // strip0 L
    f16x8 yh0 = apH[256], yh1 = apH[320], yh2 = apH[384], yh3 = apH[448];   // strip1 H
    f16x8 yl0 = apL[256], yl1 = apL[320], yl2 = apL[384], yl3 = apL[448];   // strip1 L

    int njt = (nj + 31) >> 5;
    int tpc = (njt + NCH - 1) / NCH;
    int jt0 = s * tpc, jt1 = min(jt0 + tpc, njt);
    float bv0 = -INFINITY, bv1 = -INFINITY;
    int bj0 = -1, bj1 = -1;
    const f16x8* bpH0 = (const f16x8*)bH + (size_t)b * NSTRIP * 256 + l;
    const f16x8* bpL0 = (const f16x8*)bL + (size_t)b * NSTRIP * 256 + l;

    for (int jt = jt0; jt < jt1; ++jt) {
        const f16x8* bpH = bpH0 + (size_t)jt * 256;
        const f16x8* bpL = bpL0 + (size_t)jt * 256;
        f16x8 bh0 = bpH[0], bh1 = bpH[64], bh2 = bpH[128], bh3 = bpH[192];
        f16x8 bl0 = bpL[0], bl1 = bpL[64], bl2 = bpL[128], bl3 = bpL[192];
        f32x16 cH0 = {}, cC0 = {}, cH1 = {}, cC1 = {};
        // strip 0
        cH0 = __builtin_amdgcn_mfma_f32_32x32x16_f16(bh0, xh0, cH0, 0, 0, 0);
        cC0 = __builtin_amdgcn_mfma_f32_32x32x16_f16(bh0, xl0, cC0, 0, 0, 0);
        cC0 = __builtin_amdgcn_mfma_f32_32x32x16_f16(bl0, xh0, cC0, 0, 0, 0);
        cH0 = __builtin_amdgcn_mfma_f32_32x32x16_f16(bh1, xh1, cH0, 0, 0, 0);
        cC0 = __builtin_amdgcn_mfma_f32_32x32x16_f16(bh1, xl1, cC0, 0, 0, 0);
        cC0 = __builtin_amdgcn_mfma_f32_32x32x16_f16(bl1, xh1, cC0, 0, 0, 0);
        cH0 = __builtin_amdgcn_mfma_f32_32x32x16_f16(bh2, xh2, cH0, 0, 0, 0);
        cC0 = __builtin_amdgcn_mfma_f32_32x32x16_f16(bh2, xl2, cC0, 0, 0, 0);
        cC0 = __builtin_amdgcn_mfma_f32_32x32x16_f16(bl2, xh2, cC0, 0, 0, 0);
        cH0 = __builtin_amdgcn_mfma_f32_32x32x16_f16(bh3, xh3, cH0, 0, 0, 0);
        cC0 = __builtin_amdgcn_mfma_f32_32x32x16_f16(bh3, xl3, cC0, 0, 0, 0);
        cC0 = __builtin_amdgcn_mfma_f32_32x32x16_f16(bl3, xh3, cC0, 0, 0, 0);
        // strip 1 (same b-frags)
        cH1 = __builtin_amdgcn_mfma_f32_32x32x16_f16(bh0, yh0, cH1, 0, 0, 0);
        cC1 = __builtin_amdgcn_mfma_f32_32x32x16_f16(bh0, yl0, cC1, 0, 0, 0);
        cC1 = __builtin_amdgcn_mfma_f32_32x32x16_f16(bl0, yh0, cC1, 0, 0, 0);
        cH1 = __builtin_amdgcn_mfma_f32_32x32x16_f16(bh1, yh1, cH1, 0, 0, 0);
        cC1 = __builtin_amdgcn_mfma_f32_32x32x16_f16(bh1, yl1, cC1, 0, 0, 0);
        cC1 = __builtin_amdgcn_mfma_f32_32x32x16_f16(bl1, yh1, cC1, 0, 0, 0);
        cH1 = __builtin_amdgcn_mfma_f32_32x32x16_f16(bh2, yh2, cH1, 0, 0, 0);
        cC1 = __builtin_amdgcn_mfma_f32_32x32x16_f16(bh2, yl2, cC1, 0, 0, 0);
        cC1 = __builtin_amdgcn_mfma_f32_32x32x16_f16(bl2, yh2, cC1, 0, 0, 0);
        cH1 = __builtin_amdgcn_mfma_f32_32x32x16_f16(bh3, yh3, cH1, 0, 0, 0);
        cC1 = __builtin_amdgcn_mfma_f32_32x32x16_f16(bh3, yl3, cC1, 0, 0, 0);
        cC1 = __builtin_amdgcn_mfma_f32_32x32x16_f16(bl3, yh3, cC1, 0, 0, 0);
        int jb = jt << 5;
        // scan registers in ascending-j order (strict > => first max)
#pragma unroll
        for (int r = 0; r < 16; ++r) {
            int row = (r & 3) + 8 * (r >> 2) + 4 * g;
            int j = jb + row;
            float v0 = fmaf(cC0[r], 4.8828125e-4f /*2^-11*/, cH0[r]);
            float v1 = fmaf(cC1[r], 4.8828125e-4f, cH1[r]);
            if (j < nj && v0 > bv0) { bv0 = v0; bj0 = j; }
            if (j < nj && v1 > bv1) { bv1 = v1; bj1 = j; }
        }
    }
    unsigned long long k0 = ((unsigned long long)ordf(bv0) << 32) |
                            (unsigned long long)(~(unsigned int)bj0);
    unsigned long long k1 = ((unsigned long long)ordf(bv1) << 32) |
                            (unsigned long long)(~(unsigned int)bj1);
    unsigned long long o0 = __shfl_xor(k0, 32, 64);   // merge lane halves
    unsigned long long o1 = __shfl_xor(k1, 32, 64);
    if (o0 > k0) k0 = o0;
    if (o1 > k1) k1 = o1;
    int il0 = base + ln, il1 = base + 32 + ln;
    // high word > ordf(-inf) iff at least one half found a (finite) candidate
    if (g == 0) {
        if (il0 < ni && (unsigned)(k0 >> 32) > 0x007FFFFFu)
            atomicMax(&amax[(size_t)b * HW + ilist[il0]], k0);
        if (il1 < ni && (unsigned)(k1 >> 32) > 0x007FFFFFu)
            atomicMax(&amax[(size_t)b * HW + ilist[il1]], k1);
    }
}

// ---------------- kernel 5: fused epilogue (copy + decode + gather) -------
__global__ void epilogue_kernel(const float4* __restrict__ x4, const float* __restrict__ x,
                                const int* __restrict__ mask,
                                const unsigned long long* __restrict__ amax,
                                const int* __restrict__ jlist, float4* __restrict__ out4) {
    const int q = HW / 4;                            // 2304
    int t = blockIdx.x * blockDim.x + threadIdx.x;   // 0 .. 2*192*q-1
    if (t >= 2 * 192 * q) return;
    int pos4 = t % q;
    int c = (t / q) % 192;
    int b = t / (192 * q);
    if (c < 128) {
        out4[t] = x4[((size_t)b * 128 + c) * q + pos4];
    } else {
        float4 v = make_float4(0.f, 0.f, 0.f, 0.f);
        float* vp = &v.x;
        int pos = pos4 * 4;
        const float* xf = x + (size_t)(b * 128 + (c - 128)) * HW;
#pragma unroll
        for (int k = 0; k < 4; k++) {
            int p = pos + k;
            if (mask[p] >= 1) {
                unsigned long long key = amax[(size_t)b * HW + p];
                int j = 0;                           // nj==0 -> argmax of all-NEG row = 0
                if (key != 0ull) j = jlist[(int)(~(unsigned int)key)];
                vp[k] = xf[j];
            }
        }
        out4[t] = v;
    }
}

extern "C" void kernel_launch(void* const* d_in, const int* in_sizes, int n_in,
                              void* d_out, int out_size, void* d_ws, size_t ws_size,
                              hipStream_t stream) {
    const float* x = (const float*)d_in[0];
    const int* mask = (const int*)d_in[1];
    float4* out4 = (float4*)d_out;

    // workspace layout (aH 128B-aligned):
    //   counts @0 (8B) | ilist @128 (36864) | jlist @36992 (36864)
    //   slotmap @73856 (36864) | amax @110720 (147456) | invAll @258176 (73728)
    //   aH @331904 | aL | bH | bL  -- each 2*288*4*64*8 f16 = 2359296 B
    // total = 331904 + 4*2359296 = 9769088 B
    char* ws = (char*)d_ws;
    int*   counts  = (int*)ws;
    int*   ilist   = (int*)(ws + 128);
    int*   jlist   = (int*)(ws + 36992);
    int*   slotmap = (int*)(ws + 73856);
    unsigned long long* amax = (unsigned long long*)(ws + 110720);
    float* invAll  = (float*)(ws + 258176);
    _Float16* aH = (_Float16*)(ws + 331904);
    _Float16* aL = (_Float16*)(ws + 331904 + 1 * 2359296);
    _Float16* bH = (_Float16*)(ws + 331904 + 2 * 2359296);
    _Float16* bL = (_Float16*)(ws + 331904 + 3 * 2359296);

    // 1) compaction (+ slotmap)
    compact_kernel<<<1, 1024, 0, stream>>>(mask, ilist, jlist, slotmap, counts);
    // 2) row norms (all positions, 2304 waves)
    norm_kernel<<<(2 * HW * 8) / 256, 256, 0, stream>>>(x, invAll);
    // 3) fragment-packed fp16x2 operands + amax zeroing (position-order, coalesced)
    {
        dim3 grid(HW / 256, 8, 2);                   // 36 x (ks,g) x b
        pack_kernel<<<grid, 256, 0, stream>>>(x, slotmap, invAll, aH, aL, bH, bL, amax);
    }
    // 4) MFMA argmax: grid (i-pair groups, j-chunks, batch), 64 i-rows/wave
    {
        dim3 grid(NSTRIP / 8, NCH, 2);               // 36 x 16 x 2
        argmax_kernel<<<grid, 256, 0, stream>>>(aH, aL, bH, bL, ilist, counts, amax);
    }
    // 5) fused copy + decode + gather
    {
        int n = 2 * 192 * (HW / 4);
        epilogue_kernel<<<(n + 255) / 256, 256, 0, stream>>>((const float4*)x, x, mask,
                                                             amax, jlist, out4);
    }
}